// Round 1
// baseline (449.364 us; speedup 1.0000x reference)
//
#include <hip/hip_runtime.h>

#define BB 32
#define CC 3
#define HH 512
#define WW 512
#define KK 21
#define PAD 10
#define TILE 64
#define IN_TILE 84      // TILE + KK - 1
#define LDS_STRIDE 88   // IN_TILE padded to multiple of 4 floats (16B alignment for float4)
#define KSTRIDE 24      // kernel row stride in LDS (21 -> 24, 16B aligned rows)
#define TX 16           // outputs per thread (one row, 16 consecutive x)

__global__ __launch_bounds__(256, 4) void dwconv_f32(
    const float* __restrict__ x,
    const float* __restrict__ ker,
    float* __restrict__ out)
{
    __shared__ float s_in[IN_TILE * LDS_STRIDE];
    __shared__ float s_k[KK * KSTRIDE];

    // 8x8 tiles of 64x64 per (b,c) image; 96 images -> 6144 blocks
    const int tiles_per_img = (HH / TILE) * (WW / TILE);   // 64
    const int bc = blockIdx.x / tiles_per_img;              // 0..95
    const int t  = blockIdx.x % tiles_per_img;
    const int ty0 = (t / (WW / TILE)) * TILE;
    const int tx0 = (t % (WW / TILE)) * TILE;
    const int b = bc / CC;

    const float* __restrict__ xp = x + (size_t)bc * HH * WW;
    const float* __restrict__ kp = ker + (size_t)b * KK * KK;

    const int tid = threadIdx.x;

    // ---- stage kernel (441 floats) into LDS, row stride 24 ----
    for (int i = tid; i < KK * KK; i += 256) {
        s_k[(i / KK) * KSTRIDE + (i % KK)] = kp[i];
    }

    // ---- stage 84x84 input tile (zero-padded at image borders) ----
    for (int i = tid; i < IN_TILE * IN_TILE; i += 256) {
        const int ly = i / IN_TILE;
        const int lx = i - ly * IN_TILE;
        const int gy = ty0 - PAD + ly;
        const int gx = tx0 - PAD + lx;
        float v = 0.0f;
        if (gy >= 0 && gy < HH && gx >= 0 && gx < WW) {
            v = xp[(size_t)gy * WW + gx];
        }
        s_in[ly * LDS_STRIDE + lx] = v;
    }
    __syncthreads();

    // thread -> (row 0..63, x-quarter 0..3)
    const int row = tid >> 2;
    const int xq  = (tid & 3) * TX;

    float acc[TX];
#pragma unroll
    for (int i = 0; i < TX; ++i) acc[i] = 0.0f;

#pragma unroll 1
    for (int kh = 0; kh < KK; ++kh) {
        // kernel row kh (wave-uniform broadcast reads), 24 floats via 6x float4
        float kr[24];
        {
            const float4* krp = (const float4*)&s_k[kh * KSTRIDE];
#pragma unroll
            for (int v = 0; v < 6; ++v) {
                const float4 f = krp[v];
                kr[4 * v + 0] = f.x; kr[4 * v + 1] = f.y;
                kr[4 * v + 2] = f.z; kr[4 * v + 3] = f.w;
            }
        }
        // input segment: 36 floats starting at (row+kh, xq) via 9x ds_read_b128
        float seg[36];
        {
            const float4* srow = (const float4*)&s_in[(row + kh) * LDS_STRIDE + xq];
#pragma unroll
            for (int v = 0; v < 9; ++v) {
                const float4 f = srow[v];
                seg[4 * v + 0] = f.x; seg[4 * v + 1] = f.y;
                seg[4 * v + 2] = f.z; seg[4 * v + 3] = f.w;
            }
        }
        // 21 taps x 16 outputs, all in registers
#pragma unroll
        for (int kw = 0; kw < KK; ++kw) {
            const float kv = kr[kw];
#pragma unroll
            for (int i = 0; i < TX; ++i) {
                acc[i] = fmaf(seg[kw + i], kv, acc[i]);
            }
        }
    }

    // ---- write 16 outputs as 4x float4 (coalesced, aligned) ----
    float* __restrict__ op = out + (size_t)bc * HH * WW + (size_t)(ty0 + row) * WW + (tx0 + xq);
#pragma unroll
    for (int v = 0; v < 4; ++v) {
        float4 f;
        f.x = acc[4 * v + 0]; f.y = acc[4 * v + 1];
        f.z = acc[4 * v + 2]; f.w = acc[4 * v + 3];
        ((float4*)op)[v] = f;
    }
}

extern "C" void kernel_launch(void* const* d_in, const int* in_sizes, int n_in,
                              void* d_out, int out_size, void* d_ws, size_t ws_size,
                              hipStream_t stream) {
    const float* x   = (const float*)d_in[0];
    const float* ker = (const float*)d_in[1];
    float* out = (float*)d_out;

    const int tiles_per_img = (HH / TILE) * (WW / TILE);  // 64
    const int nblocks = BB * CC * tiles_per_img;          // 6144

    dwconv_f32<<<nblocks, 256, 0, stream>>>(x, ker, out);
}

// Round 2
// 424.760 us; speedup vs baseline: 1.0579x; 1.0579x over previous
//
#include <hip/hip_runtime.h>

#define BB 32
#define CC 3
#define HH 512
#define WW 512
#define KK 21
#define PAD 10
#define TILE 64
#define IN_TILE 84      // TILE + KK - 1
// LDS row stride in words: 92. 92/4 = 23 == 7 (mod 8) -> coprime with the 8
// 16B quad-banks, so the 16 rows a wave touches cycle all 8 quad-banks and a
// wave64 ds_read_b128 hits the minimal 8 phases. (88 gave gcd=2 -> 16 extra
// cycles/instr, SQ_LDS_BANK_CONFLICT=1.3e8.)
#define LDS_STRIDE 92
#define KSTRIDE 24      // kernel row stride in LDS (21 -> 24, 16B aligned rows)
#define TX 16           // outputs per thread (one row, 16 consecutive x)

__global__ __launch_bounds__(256, 4) void dwconv_f32(
    const float* __restrict__ x,
    const float* __restrict__ ker,
    float* __restrict__ out)
{
    __shared__ float s_in[IN_TILE * LDS_STRIDE];
    __shared__ float s_k[KK * KSTRIDE];

    // 8x8 tiles of 64x64 per (b,c) image; 96 images -> 6144 blocks
    const int tiles_per_img = (HH / TILE) * (WW / TILE);   // 64
    const int bc = blockIdx.x / tiles_per_img;              // 0..95
    const int t  = blockIdx.x % tiles_per_img;
    const int ty0 = (t / (WW / TILE)) * TILE;
    const int tx0 = (t % (WW / TILE)) * TILE;
    const int b = bc / CC;

    const float* __restrict__ xp = x + (size_t)bc * HH * WW;
    const float* __restrict__ kp = ker + (size_t)b * KK * KK;

    const int tid = threadIdx.x;

    // ---- stage kernel (441 floats) into LDS, row stride 24 ----
    for (int i = tid; i < KK * KK; i += 256) {
        s_k[(i / KK) * KSTRIDE + (i % KK)] = kp[i];
    }

    // ---- stage 84x84 input tile (zero-padded at image borders) ----
    for (int i = tid; i < IN_TILE * IN_TILE; i += 256) {
        const int ly = i / IN_TILE;
        const int lx = i - ly * IN_TILE;
        const int gy = ty0 - PAD + ly;
        const int gx = tx0 - PAD + lx;
        float v = 0.0f;
        if (gy >= 0 && gy < HH && gx >= 0 && gx < WW) {
            v = xp[(size_t)gy * WW + gx];
        }
        s_in[ly * LDS_STRIDE + lx] = v;
    }
    __syncthreads();

    // thread -> (row 0..63, x-quarter 0..3)
    const int row = tid >> 2;
    const int xq  = (tid & 3) * TX;

    float acc[TX];
#pragma unroll
    for (int i = 0; i < TX; ++i) acc[i] = 0.0f;

#pragma unroll 1
    for (int kh = 0; kh < KK; ++kh) {
        // kernel row kh (wave-uniform broadcast reads), 24 floats via 6x float4
        float kr[24];
        {
            const float4* krp = (const float4*)&s_k[kh * KSTRIDE];
#pragma unroll
            for (int v = 0; v < 6; ++v) {
                const float4 f = krp[v];
                kr[4 * v + 0] = f.x; kr[4 * v + 1] = f.y;
                kr[4 * v + 2] = f.z; kr[4 * v + 3] = f.w;
            }
        }
        // input segment: 36 floats starting at (row+kh, xq) via 9x ds_read_b128
        float seg[36];
        {
            const float4* srow = (const float4*)&s_in[(row + kh) * LDS_STRIDE + xq];
#pragma unroll
            for (int v = 0; v < 9; ++v) {
                const float4 f = srow[v];
                seg[4 * v + 0] = f.x; seg[4 * v + 1] = f.y;
                seg[4 * v + 2] = f.z; seg[4 * v + 3] = f.w;
            }
        }
        // 21 taps x 16 outputs, all in registers
#pragma unroll
        for (int kw = 0; kw < KK; ++kw) {
            const float kv = kr[kw];
#pragma unroll
            for (int i = 0; i < TX; ++i) {
                acc[i] = fmaf(seg[kw + i], kv, acc[i]);
            }
        }
    }

    // ---- write 16 outputs as 4x float4 (coalesced, aligned) ----
    float* __restrict__ op = out + (size_t)bc * HH * WW + (size_t)(ty0 + row) * WW + (tx0 + xq);
#pragma unroll
    for (int v = 0; v < 4; ++v) {
        float4 f;
        f.x = acc[4 * v + 0]; f.y = acc[4 * v + 1];
        f.z = acc[4 * v + 2]; f.w = acc[4 * v + 3];
        ((float4*)op)[v] = f;
    }
}

extern "C" void kernel_launch(void* const* d_in, const int* in_sizes, int n_in,
                              void* d_out, int out_size, void* d_ws, size_t ws_size,
                              hipStream_t stream) {
    const float* x   = (const float*)d_in[0];
    const float* ker = (const float*)d_in[1];
    float* out = (float*)d_out;

    const int tiles_per_img = (HH / TILE) * (WW / TILE);  // 64
    const int nblocks = BB * CC * tiles_per_img;          // 6144

    dwconv_f32<<<nblocks, 256, 0, stream>>>(x, ker, out);
}